// Round 5
// baseline (636.014 us; speedup 1.0000x reference)
//
#include <hip/hip_runtime.h>
#include <hip/hip_cooperative_groups.h>
#include <math.h>

namespace cg = cooperative_groups;

typedef unsigned int u32;
typedef unsigned long long u64;

#define NPIX 6291456
#define NBLK 768
#define NTHR 256

// ---------------- ws layout ----------------
//     0: scale[32] f32      (phase 3)
//   128: madsum f32         (zeroed phase 0, atomicAdd phase 4)
//   384: selBin[32] u32     (phase 1)
//   512: selKr[32] u32      (phase 1)
//  1024: arts, 4 bf16 planes of NPIX packed as u32[2*NPIX] = 50.33 MB
//        ALIASED scratch (dead until phase 4 writes arts):
//          ghist   = arts + 0        : [768][4096] u32 = 12 MB
//          members = arts + 3145728  : [768][8192] u32 = 24 MB
//          scount  = arts + 9437184  : [768] u32
// LDS union (33.8 KB): hist 16KB | extract sbuf 32KB | select sbuf+h+wtot+misc
//          | denoise sex 10.25KB + red | binsel wtot

__device__ __forceinline__ float med3f(float a, float b, float c) {
    return fmaxf(fminf(a, b), fminf(fmaxf(a, b), c));
}
__device__ __forceinline__ float med5f(float a0, float a1, float a2, float a3, float a4) {
    float mn01 = fminf(a0, a1), mx01 = fmaxf(a0, a1);
    float mn34 = fminf(a3, a4), mx34 = fmaxf(a3, a4);
    return med3f(a2, fmaxf(mn01, mn34), fminf(mx01, mx34));
}
__device__ __forceinline__ u32 packbf(float lo, float hi) {
    u32 a = __float_as_uint(lo), b = __float_as_uint(hi);
    a = (a + 0x7FFFu + ((a >> 16) & 1u)) >> 16;
    b = (b + 0x7FFFu + ((b >> 16) & 1u)) >> 16;
    return a | (b << 16);
}

// inclusive scan over 256 threads (4 waves); wtot = 16-entry LDS
__device__ __forceinline__ u32 scan256(u32 v, u32* wtot) {
    int lane = threadIdx.x & 63, wid = threadIdx.x >> 6;
    u32 inc = v;
    #pragma unroll
    for (int off = 1; off < 64; off <<= 1) {
        u32 o = __shfl_up(inc, off);
        if (lane >= off) inc += o;
    }
    __syncthreads();                 // WAR protection for wtot reuse
    if (lane == 63) wtot[wid] = inc;
    __syncthreads();
    for (int w = 0; w < wid; ++w) inc += wtot[w];
    return inc;
}

// ---------------- phase 0: per-slice 12-bit histograms ----------------
// 768 blocks = 32 batches x 24 slices of 8192 floats. Plain writes, no atomics.

__device__ void phase_hist(const float* __restrict__ x, u32* ghist,
                           float* madsum, u32* shraw) {
    int blk = blockIdx.x, t = threadIdx.x;
    int b = blk / 24, s = blk % 24;
    u32* lh = shraw;
    uint4 z = make_uint4(0u, 0u, 0u, 0u);
    #pragma unroll
    for (int j = 0; j < 4; ++j) ((uint4*)lh)[t + j * 256] = z;
    __syncthreads();
    const float4* xb = (const float4*)(x + (size_t)b * 196608 + s * 8192);
    #pragma unroll
    for (int i = 0; i < 8; ++i) {
        float4 v = xb[t + i * 256];
        atomicAdd(&lh[__float_as_uint(fabsf(v.x)) >> 19], 1u);
        atomicAdd(&lh[__float_as_uint(fabsf(v.y)) >> 19], 1u);
        atomicAdd(&lh[__float_as_uint(fabsf(v.z)) >> 19], 1u);
        atomicAdd(&lh[__float_as_uint(fabsf(v.w)) >> 19], 1u);
    }
    __syncthreads();
    uint4* ghb = (uint4*)(ghist + (size_t)blk * 4096);
    #pragma unroll
    for (int j = 0; j < 4; ++j) ghb[t + j * 256] = ((uint4*)lh)[t + j * 256];
    if (blk == 0 && t == 0) *madsum = 0.0f;
}

// ---------------- phase 1: per-batch median bin selection (32 blocks) --------

__device__ void phase_binsel(const u32* ghist, u32* selBin, u32* selKr,
                             u32* shraw) {
    int blk = blockIdx.x;
    if (blk >= 32) return;
    int t = threadIdx.x;
    u32* wtot = shraw;
    u32 s16[16];
    #pragma unroll
    for (int j = 0; j < 16; ++j) s16[j] = 0u;
    const u32* hb = ghist + (size_t)blk * 24 * 4096;
    for (int sl = 0; sl < 24; ++sl) {
        const uint4* hp = (const uint4*)(hb + sl * 4096);
        #pragma unroll
        for (int j = 0; j < 4; ++j) {
            uint4 h4 = hp[t * 4 + j];
            s16[4 * j + 0] += h4.x; s16[4 * j + 1] += h4.y;
            s16[4 * j + 2] += h4.z; s16[4 * j + 3] += h4.w;
        }
    }
    u32 sum = 0;
    #pragma unroll
    for (int j = 0; j < 16; ++j) sum += s16[j];
    u32 inc = scan256(sum, wtot);
    u32 exc = inc - sum;
    u32 k = 98303u;                  // lower median rank of 196608
    if (exc <= k && k < inc) {
        u32 kr = k - exc, acc = 0u;
        #pragma unroll
        for (int j = 0; j < 16; ++j) {    // static-index walk (no scratch)
            u32 nacc = acc + s16[j];
            if (kr >= acc && kr < nacc) {
                selBin[blk] = (u32)(t * 16 + j);
                selKr[blk] = kr - acc;
            }
            acc = nacc;
        }
    }
}

// ---------------- phase 2: extract bin-member suffixes (768 blocks) ----------
// LDS ballot-compaction, one coalesced per-slice write-out, no global atomics.

__device__ void phase_extract(const float* __restrict__ x, const u32* selBin,
                              u32* members, u32* scount, u32* shraw) {
    int blk = blockIdx.x, t = threadIdx.x, lane = t & 63;
    int b = blk / 24, s = blk % 24;
    u32* sbuf = shraw;
    u32* lcnt = shraw + 8192;
    if (t == 0) *lcnt = 0u;
    u32 bin = selBin[b];
    __syncthreads();
    const float4* xb = (const float4*)(x + (size_t)b * 196608 + s * 8192);
    #pragma unroll 2
    for (int i = 0; i < 8; ++i) {
        float4 v = xb[t + i * 256];
        float vv[4] = {v.x, v.y, v.z, v.w};
        #pragma unroll
        for (int e = 0; e < 4; ++e) {
            u32 bits = __float_as_uint(fabsf(vv[e]));
            bool is = (bits >> 19) == bin;
            u64 ball = __ballot(is);
            if (ball) {
                u32 cnt = (u32)__popcll(ball);
                u32 base = 0;
                if (lane == 0) base = atomicAdd(lcnt, cnt);
                base = __shfl(base, 0);
                if (is) {
                    u32 p = base + (u32)__popcll(ball & ((1ull << lane) - 1ull));
                    if (p < 8192u) sbuf[p] = bits & 0x7FFFFu;
                }
            }
        }
    }
    __syncthreads();
    u32 cnt = *lcnt; if (cnt > 8192u) cnt = 8192u;
    u32* mb = members + (size_t)blk * 8192;
    for (u32 i = (u32)t; i < cnt; i += 256u) mb[i] = sbuf[i];
    if (t == 0) scount[blk] = cnt;
}

// ---------------- phase 3: 19-bit radix select (32 blocks) -------------------

__device__ void phase_select(const u32* scount, const u32* members,
                             const u32* selBin, const u32* selKr,
                             float* scale, u32* shraw) {
    int blk = blockIdx.x;
    if (blk >= 32) return;
    int t = threadIdx.x;
    u32* sbuf = shraw;                 // [0,8192)
    u32* h    = shraw + 8192;          // [8192,8320)
    u32* wtot = shraw + 8320;          // [8320,8336)
    u32* soff = shraw + 8336;          // [8336,8361): off[24] + total
    u32* sPfx = shraw + 8364;
    u32* sK   = shraw + 8365;
    if (t == 0) {
        u32 acc = 0u;
        for (int sl = 0; sl < 24; ++sl) { soff[sl] = acc; acc += scount[blk * 24 + sl]; }
        soff[24] = acc;
        *sPfx = 0u;
        *sK = selKr[blk];
    }
    __syncthreads();
    for (int sl = 0; sl < 24; ++sl) {
        u32 off = soff[sl], c = soff[sl + 1] - off;
        const u32* mb = members + (size_t)(blk * 24 + sl) * 8192;
        for (u32 i = (u32)t; i < c; i += 256u) {
            u32 p = off + i;
            if (p < 8192u) sbuf[p] = mb[i];
        }
    }
    u32 m = soff[24]; if (m > 8192u) m = 8192u;
    __syncthreads();
    const int shf[3] = {12, 6, 0};
    const int wd[3]  = {7, 6, 6};
    const u32 msk[3] = {127u, 63u, 63u};
    #pragma unroll 1
    for (int rd = 0; rd < 3; ++rd) {
        u32 pfx = *sPfx, k2 = *sK;
        if (t < 128) h[t] = 0u;
        __syncthreads();
        for (u32 i = (u32)t; i < m; i += 256u) {
            u32 v = sbuf[i];
            if ((v >> (shf[rd] + wd[rd])) == pfx)
                atomicAdd(&h[(v >> shf[rd]) & msk[rd]], 1u);
        }
        __syncthreads();
        u32 nb = msk[rd] + 1u;
        u32 cc = ((u32)t < nb) ? h[t] : 0u;
        u32 inc2 = scan256(cc, wtot);
        u32 exc2 = inc2 - cc;
        if ((u32)t < nb && exc2 <= k2 && k2 < inc2) {
            *sPfx = (pfx << wd[rd]) | (u32)t;
            *sK = k2 - exc2;
        }
        __syncthreads();
    }
    if (t == 0)
        scale[blk] = __uint_as_float((selBin[blk] << 19) | *sPfx) + 1e-8f;
}

// ---------------- phase 4: denoise (768 blocks = 96 img x 8 segs of 32 rows) --
// identity: huber_tv(x/s, lam, del) * s == huber_tv(x, lam*s, del*s)

__device__ __forceinline__ float dpp_shl1(float v) {   // lane i <- lane i+1 (edge -> 0)
    return __uint_as_float((u32)__builtin_amdgcn_update_dpp(
        0, (int)__float_as_uint(v), 0x130, 0xF, 0xF, true));   // wave_shl:1
}
__device__ __forceinline__ float dpp_shr1(float v) {   // lane i <- lane i-1 (edge -> 0)
    return __uint_as_float((u32)__builtin_amdgcn_update_dpp(
        0, (int)__float_as_uint(v), 0x138, 0xF, 0xF, true));   // wave_shr:1
}
__device__ __forceinline__ float hub(float d, float del) {
    return d * __builtin_amdgcn_rcpf(del + fabsf(d));
}
__device__ __forceinline__ float upd(float b, float xn, float dv, float lam) {
    float t = fmaf(-lam, dv, b - xn);
    return fmaf(-0.2f, t, b);
}

__device__ __forceinline__ float4 stage4(float4 B, float4 C, float4 xn, float4& gyp,
                                         int row, float mR3, float mL0,
                                         float lam, float del) {
    float mr = (row < 255) ? 1.f : 0.f;   // wave-uniform: dy pad 0 at last row
    float m0 = (row == 0) ? 0.f : 1.f;    // div_y[0] = gy[0]
    float gy0 = hub(C.x - B.x, del) * mr;
    float gy1 = hub(C.y - B.y, del) * mr;
    float gy2 = hub(C.z - B.z, del) * mr;
    float gy3 = hub(C.w - B.w, del) * mr;
    float dv0 = gy0 - gyp.x * m0;
    float dv1 = gy1 - gyp.y * m0;
    float dv2 = gy2 - gyp.z * m0;
    float dv3 = gy3 - gyp.w * m0;
    gyp.x = gy0; gyp.y = gy1; gyp.z = gy2; gyp.w = gy3;
    float B0n = dpp_shl1(B.x);                  // next lane's col0 (= own col3+1)
    float g01 = hub(B.y - B.x, del);
    float g12 = hub(B.z - B.y, del);
    float g23 = hub(B.w - B.z, del);
    float g3n = hub(B0n - B.w, del) * mR3;      // 0 at global col 255
    float gp  = dpp_shr1(g3n) * mL0;            // prev lane's g3n; div_x[0] = gx[0]
    float4 o;
    o.x = upd(B.x, xn.x, (g01 - gp)  + dv0, lam);
    o.y = upd(B.y, xn.y, (g12 - g01) + dv1, lam);
    o.z = upd(B.z, xn.z, (g23 - g12) + dv2, lam);
    o.w = upd(B.w, xn.w, (g3n - g23) + dv3, lam);
    return o;
}

__device__ void phase_denoise(const float* __restrict__ x, const float* scale,
                              u32* arts, float* madsum,
                              float4 lam4, float4 del4, u32* shraw) {
    float* sexf = (float*)shraw;     // [2][5][256] double-buffered exchange
    float* red  = sexf + 2560;       // [4]
    int t = threadIdx.x, lane = t & 63, wid = t >> 6;   // wid = view
    int img = blockIdx.x >> 3;       // 96 images
    int seg = blockIdx.x & 7;        // 8 row-segments of 32 rows
    float sc = scale[img / 3];
    float lam = ((wid == 0) ? lam4.x : (wid == 1) ? lam4.y : (wid == 2) ? lam4.z : lam4.w) * sc;
    float del = ((wid == 0) ? del4.x : (wid == 1) ? del4.y : (wid == 2) ? del4.z : del4.w) * sc;
    float mR3 = (lane == 63) ? 0.f : 1.f;
    float mL0 = (lane == 0) ? 0.f : 1.f;
    const float4* xp = (const float4*)(x + (size_t)img * 65536) + lane;  // row r: xp[r<<6]
    u32* ap = arts + (size_t)wid * (NPIX / 2) + (size_t)img * 32768 + lane * 2;

    float4 z4 = {0.f, 0.f, 0.f, 0.f};
    float4 cur1 = z4, cur2 = z4, gyp1 = z4, gyp2 = z4, gyp3 = z4;
    float4 n0 = z4, n1 = z4, n2 = z4;
    int out_lo = seg * 32, out_hi = out_lo + 31;
    int rs = (out_lo >= 3) ? out_lo - 3 : 0;   // 3-row pipeline warm-up
    int rend = out_hi + 3;                     // 3-step flush
    float msum = 0.f;

    float4 nl = xp[rs << 6];
    for (int r = rs; r <= rend; ++r) {
        int rn = (r + 1 <= 255) ? r + 1 : 255;
        float4 nxt = xp[rn << 6];   // prefetch (clamped; value unused past row 255)
        int r1 = r - 1, r2 = r - 2, r3 = r - 3;
        float4 x1 = stage4(n0,   nl, n0, gyp1, r1, mR3, mL0, lam, del);
        float4 x2 = stage4(cur1, x1, n1, gyp2, r2, mR3, mL0, lam, del);
        float4 x3 = stage4(cur2, x2, n2, gyp3, r3, mR3, mL0, lam, del);
        cur1 = x1; cur2 = x2;
        if (r3 >= out_lo) {   // block-uniform; r3 <= out_hi by loop bound
            uint2 pk;
            pk.x = packbf(x3.x, x3.y);
            pk.y = packbf(x3.z, x3.w);
            *(uint2*)(ap + (r3 << 7)) = pk;
            // mad exchange, double-buffered by row parity: one sync per row
            int pb = r3 & 1;
            *(float4*)&sexf[pb * 1280 + (wid + 1) * 256 + lane * 4] = x3;
            if (wid == 0) *(float4*)&sexf[pb * 1280 + lane * 4] = n2;
            __syncthreads();
            int c = wid * 64 + lane;
            float a0 = sexf[pb * 1280 + c],       a1 = sexf[pb * 1280 + 256 + c];
            float a2 = sexf[pb * 1280 + 512 + c], a3 = sexf[pb * 1280 + 768 + c];
            float a4 = sexf[pb * 1280 + 1024 + c];
            float med = med5f(a0, a1, a2, a3, a4);
            msum += med5f(fabsf(a0 - med), fabsf(a1 - med), fabsf(a2 - med),
                          fabsf(a3 - med), fabsf(a4 - med));
        }
        n2 = n1; n1 = n0; n0 = nl;
        nl = nxt;
    }
    #pragma unroll
    for (int off = 32; off > 0; off >>= 1) msum += __shfl_down(msum, off);
    if (lane == 0) red[wid] = msum;
    __syncthreads();
    if (t == 0) atomicAdd(madsum, red[0] + red[1] + red[2] + red[3]);
}

// ---------------- phase 5: fusion (grid-stride, 4 px/thread) ----------------

__device__ void phase_fuse(const float* __restrict__ x, const u32* artsU,
                           const float* madsum, float* __restrict__ out) {
    float floorv = 0.1f * (*madsum) * (1.0f / 6291456.0f);
    for (u32 t = blockIdx.x * 256u + threadIdx.x; t < NPIX / 4; t += NBLK * NTHR) {
        float4 xv = ((const float4*)x)[t];
        uint2 q0 = ((const uint2*)(artsU))[t];
        uint2 q1 = ((const uint2*)(artsU + NPIX / 2))[t];
        uint2 q2 = ((const uint2*)(artsU + NPIX))[t];
        uint2 q3 = ((const uint2*)(artsU + 3 * (NPIX / 2)))[t];
        float4 o;
#define FUSE1(res, A0, U0, U1, U2, U3, SH) { \
        float a0 = A0; \
        float a1 = __uint_as_float(SH(U0)), a2 = __uint_as_float(SH(U1)); \
        float a3 = __uint_as_float(SH(U2)), a4 = __uint_as_float(SH(U3)); \
        float med = med5f(a0, a1, a2, a3, a4); \
        float d0 = fabsf(a0 - med), d1 = fabsf(a1 - med), d2 = fabsf(a2 - med); \
        float d3 = fabsf(a3 - med), d4 = fabsf(a4 - med); \
        float mad = med5f(d0, d1, d2, d3, d4); \
        float mm = fmaxf(mad, floorv); \
        float inv = 0.5f / mm; \
        float w0 = __expf(-d0 * inv), w1 = __expf(-d1 * inv), w2 = __expf(-d2 * inv); \
        float w3 = __expf(-d3 * inv), w4 = __expf(-d4 * inv); \
        float swt = w0 + w1 + w2 + w3 + w4; \
        float sva = fmaf(w0, a0, fmaf(w1, a1, fmaf(w2, a2, fmaf(w3, a3, w4 * a4)))); \
        res = sva / (swt + 1e-8f); \
    }
#define LO16(u) ((u) << 16)
#define HI16(u) ((u) & 0xFFFF0000u)
        FUSE1(o.x, xv.x, q0.x, q1.x, q2.x, q3.x, LO16);
        FUSE1(o.y, xv.y, q0.x, q1.x, q2.x, q3.x, HI16);
        FUSE1(o.z, xv.z, q0.y, q1.y, q2.y, q3.y, LO16);
        FUSE1(o.w, xv.w, q0.y, q1.y, q2.y, q3.y, HI16);
#undef FUSE1
#undef LO16
#undef HI16
        ((float4*)out)[t] = o;
    }
}

// ---------------- mega kernel: all phases, grid.sync between -----------------

__global__ __launch_bounds__(256, 4) void mega_kernel(
        const float* __restrict__ x, float* __restrict__ out,
        float* scale, float* madsum, u32* selBin, u32* selKr,
        u32* ghist, u32* members, u32* scount, u32* arts,
        float4 lam4, float4 del4, int plo, int phi) {
    __shared__ __align__(16) u32 shraw[8448];   // 33.8 KB union -> 4 blocks/CU
    cg::grid_group grid = cg::this_grid();
    for (int p = plo; p <= phi; ++p) {
        switch (p) {
            case 0: phase_hist(x, ghist, madsum, shraw); break;
            case 1: phase_binsel(ghist, selBin, selKr, shraw); break;
            case 2: phase_extract(x, selBin, members, scount, shraw); break;
            case 3: phase_select(scount, members, selBin, selKr, scale, shraw); break;
            case 4: phase_denoise(x, scale, arts, madsum, lam4, del4, shraw); break;
            case 5: phase_fuse(x, arts, madsum, out); break;
        }
        if (p < phi) grid.sync();
    }
}

// ---------------- launch ----------------

extern "C" void kernel_launch(void* const* d_in, const int* in_sizes, int n_in,
                              void* d_out, int out_size, void* d_ws, size_t ws_size,
                              hipStream_t stream) {
    const float* x = (const float*)d_in[0];
    float* out = (float*)d_out;
    char* ws = (char*)d_ws;
    float* scale  = (float*)ws;
    float* madsum = (float*)(ws + 128);
    u32* selBin   = (u32*)(ws + 384);
    u32* selKr    = (u32*)(ws + 512);
    u32* artsU    = (u32*)(ws + 1024);
    // scratch aliases the arts region (dead until phase 4 writes arts)
    u32* ghist    = artsU;                       // 12 MB
    u32* members  = artsU + (size_t)3145728;     // 24 MB
    u32* scount   = artsU + (size_t)9437184;     // 3 KB

    float lamf[4], delf[4];
    for (int i = 0; i < 4; ++i) {
        double lam = 0.025 + 0.05 * (double)i / 3.0;
        lamf[i] = (float)lam;
        delf[i] = (float)(0.01 * sqrt(lam / (0.05 + 1e-8)));
    }
    float4 lam4 = make_float4(lamf[0], lamf[1], lamf[2], lamf[3]);
    float4 del4 = make_float4(delf[0], delf[1], delf[2], delf[3]);

    int plo = 0, phi = 5;
    void* kargs[] = {(void*)&x, (void*)&out, (void*)&scale, (void*)&madsum,
                     (void*)&selBin, (void*)&selKr, (void*)&ghist, (void*)&members,
                     (void*)&scount, (void*)&artsU, (void*)&lam4, (void*)&del4,
                     (void*)&plo, (void*)&phi};
    hipError_t e = hipLaunchCooperativeKernel((void*)mega_kernel,
                       dim3(NBLK), dim3(NTHR), kargs, 0, stream);
    if (e != hipSuccess) {
        (void)hipGetLastError();
        // fallback: one plain launch per phase (kernel boundaries = sync)
        for (int p = 0; p < 6; ++p)
            mega_kernel<<<NBLK, NTHR, 0, stream>>>(x, out, scale, madsum,
                selBin, selKr, ghist, members, scount, artsU, lam4, del4, p, p);
    }
}